// Round 10
// baseline (264.510 us; speedup 1.0000x reference)
//
#include <hip/hip_runtime.h>
#include <cstdint>

// Fully-fused GRU: B=2048, T=256, F=64, H=32. fp32 in/out. ONE kernel.
// 256 blocks x 192 thr = 3 waves/block, 1 block/CU:
//   wave 0 (chain): TWO independent 4-batch GRU sets (A=b0..3, B=b0+4..7),
//     statement-interleaved so B's issue fills A's dep-latency gaps (and vice
//     versa). r4-r8 triangulation: with 1 wave/SIMD, step time ~= 6cy x
//     (VALU ops on the serial chain) + MFMA; in-wave 2-set ILP halves the
//     effective latency per step. Acts = r7's lean form (raw v_exp_f32 via
//     __builtin_amdgcn_exp2f, pair-batched v_rcp, v_cvt_pk_bf16_f32 pack,
//     4x v_mov_dpp quad_perm B-frag all-gather; zero memory ops on chain).
//   waves 1,2 (producers): each stages ONE set, byte-identical to r7's
//     producer: ring x-loads, hi/lo bf16 split, 24 x-proj MFMAs/group,
//     double-buffered LDS [col][gate] (CSTRIDE=104), one group ahead.
//   Barriers: raw s_barrier + lgkmcnt(0) only (65 total) — producer HBM
//   prefetch stays in flight across barriers. Per-set numerics == r7.

#define TSEQ 256
#define CSTRIDE 104                                // floats per col (16B aligned)

typedef __attribute__((ext_vector_type(8))) short bf16x8;
typedef __attribute__((ext_vector_type(4))) float f32x4;
union BF8 { unsigned u[4]; bf16x8 v; };

__device__ __forceinline__ unsigned bfr(float f) {            // bf16 RNE in hi16
    unsigned u = __float_as_uint(f);
    return u + 0x7fffu + ((u >> 16) & 1u);
}
__device__ __forceinline__ unsigned packhi(unsigned a, unsigned b) {
    return __builtin_amdgcn_perm(b, a, 0x07060302u);          // hi16(a)|hi16(b)<<16
}
// 8 fp32 -> hi (truncated bf16) + lo (bf16 of residual): 3-term-quality products
__device__ __forceinline__ void cvt2(const float4& f0, const float4& f1,
                                     bf16x8& hi, bf16x8& lo) {
    float f[8] = {f0.x,f0.y,f0.z,f0.w, f1.x,f1.y,f1.z,f1.w};
    BF8 H, L;
    #pragma unroll
    for (int d = 0; d < 4; ++d) {
        float a = f[2*d], b = f[2*d+1];
        unsigned ua = __float_as_uint(a), ub = __float_as_uint(b);
        float ra = a - __uint_as_float(ua & 0xffff0000u);
        float rb = b - __uint_as_float(ub & 0xffff0000u);
        H.u[d] = packhi(ua, ub);
        L.u[d] = packhi(bfr(ra), bfr(rb));
    }
    hi = H.v; lo = L.v;
}
__device__ __forceinline__ float sel4(f32x4 v, int u) {
    float a = (u & 1) ? v[1] : v[0];
    float b = (u & 1) ? v[3] : v[2];
    return (u & 2) ? b : a;
}

#define MFMA16(A, B, C) __builtin_amdgcn_mfma_f32_16x16x32_bf16((A), (B), (C), 0, 0, 0)

// quad_perm broadcast of lane w within each aligned 4-lane quad (pure VALU).
#define QBCAST(x, w) ((unsigned)__builtin_amdgcn_update_dpp( \
        0, (int)(x), ((w) | ((w)<<2) | ((w)<<4) | ((w)<<6)), 0xf, 0xf, true))

// barrier WITHOUT the compiler's vmcnt(0) drain: producers' in-flight HBM
// prefetch (needed a full group later) survives the sync.
__device__ __forceinline__ void barrier_nodrain() {
    asm volatile("s_waitcnt lgkmcnt(0)" ::: "memory");
    __builtin_amdgcn_s_barrier();
    asm volatile("" ::: "memory");
}

__global__ __launch_bounds__(192, 1)
void gru_fused(const float* __restrict__ x, const float* __restrict__ W_ih,
               const float* __restrict__ W_hh, const float* __restrict__ b_ih,
               const float* __restrict__ b_hh, const float* __restrict__ W_head,
               const float* __restrict__ b_head, float* __restrict__ out)
{
    // [buf][set][col*CSTRIDE + nt*16 + q*4 + r]; col = batch + 4*step
    __shared__ float xsh[2][2][16 * CSTRIDE];
    const int tid  = threadIdx.x;
    const int wid  = tid >> 6;                     // 0 = chain; 1,2 = producers
    const int lane = tid & 63;
    const int m = lane & 15, q = lane >> 4;
    const int b0 = blockIdx.x * 8;

    if (wid >= 1) {
        // ===================== producer (set pq) =====================
        const int pq = wid - 1;
        const int bq = m & 3, u = m >> 2;          // col m = (batch bq, step u)
        bf16x8 Aih[6][2];
        #pragma unroll
        for (int nt = 0; nt < 6; ++nt)
            #pragma unroll
            for (int c = 0; c < 2; ++c) {
                const float* wp = W_ih + (nt*16 + m)*64 + c*32 + q*8;
                BF8 t;
                #pragma unroll
                for (int d = 0; d < 4; ++d) t.u[d] = packhi(bfr(wp[2*d]), bfr(wp[2*d+1]));
                Aih[nt][c] = t.v;
            }
        float4 ring[4];
        const float* xcol = x + ((size_t)(b0 + pq*4 + bq)*TSEQ + u)*64 + q*8;
        auto ldring = [&](int grp) {
            const float* p = xcol + grp*256;       // grp*4 steps * 64 floats
            ring[0] = ((const float4*)p)[0];        ring[1] = ((const float4*)p)[1];
            ring[2] = ((const float4*)(p+32))[0];   ring[3] = ((const float4*)(p+32))[1];
        };
        auto projwrite = [&](int buf) {            // ring -> x-proj -> LDS[buf]
            bf16x8 Xh0, Xl0, Xh1, Xl1;
            cvt2(ring[0], ring[1], Xh0, Xl0);
            cvt2(ring[2], ring[3], Xh1, Xl1);
            #pragma unroll
            for (int nt = 0; nt < 6; ++nt) {
                f32x4 a = MFMA16(Aih[nt][0], Xh0, ((f32x4){0.f,0.f,0.f,0.f}));
                a = MFMA16(Aih[nt][0], Xl0, a);
                a = MFMA16(Aih[nt][1], Xh1, a);
                a = MFMA16(Aih[nt][1], Xl1, a);
                *(f32x4*)&xsh[buf][pq][m*CSTRIDE + nt*16 + q*4] = a;   // 16B aligned
            }
        };
        ldring(0);
        projwrite(0);                              // group-0 data into buf 0
        ldring(1);
        barrier_nodrain();                         // buf0 ready
        for (int g = 0; g < 64; ++g) {
            if (g < 63) {
                projwrite((g + 1) & 1);            // chain is in buf[g&1]
                ldring(g + 2 < 64 ? g + 2 : 63);
            }
            barrier_nodrain();
        }
    } else {
        // ========== chain: sets A and B, statement-interleaved ==========
        const int bq = m >> 2, u = m & 3;          // replicas = consecutive lanes
        // ---- W_hh A-frags, K-permuted: pos p=q*8+j <-> dim (p>>1)+16*(p&1)
        bf16x8 Awh[6];
        #pragma unroll
        for (int nt = 0; nt < 6; ++nt) {
            const float* wp = W_hh + (nt*16 + m)*32;
            BF8 t;
            #pragma unroll
            for (int d = 0; d < 4; ++d) {
                int dd = q*4 + d;
                t.u[d] = packhi(bfr(wp[dd]), bfr(wp[dd + 16]));
            }
            Awh[nt] = t.v;
        }
        // ---- biases: C-init vectors (component reg <-> gate nt*16+q*4+reg)
        f32x4 FRZ[4], BN0, BN1;
        #pragma unroll
        for (int nt = 0; nt < 4; ++nt) {
            f32x4 t;
            #pragma unroll
            for (int r = 0; r < 4; ++r) { int g = nt*16 + q*4 + r; t[r] = b_ih[g] + b_hh[g]; }
            FRZ[nt] = t;
        }
        #pragma unroll
        for (int r = 0; r < 4; ++r) { BN0[r] = b_hh[64+q*4+r]; BN1[r] = b_hh[80+q*4+r]; }
        const float fn0 = b_ih[64 + q*4 + u], fn1 = b_ih[80 + q*4 + u];

        unsigned HdA[4] = {0u,0u,0u,0u}, HdB[4] = {0u,0u,0u,0u};
        float hAL = 0.f, hAH = 0.f, hBL = 0.f, hBH = 0.f;
        barrier_nodrain();                         // buf0 ready

        const float KS = -1.4426950408889634f;     // -log2(e)   (sigmoid)
        const float KT = -2.8853900817779268f;     // -2*log2(e) (tanh)
        for (int g = 0; g < 64; ++g) {
            const int cbuf = g & 1;
            // group's x-pre scalars for BOTH sets: 48 ds_read_b32, off-chain
            float xpA[4][6], xpB[4][6];
            #pragma unroll
            for (int s = 0; s < 4; ++s) {
                const float* rpA = &xsh[cbuf][0][(bq + 4*s)*CSTRIDE + q*4 + u];
                const float* rpB = &xsh[cbuf][1][(bq + 4*s)*CSTRIDE + q*4 + u];
                #pragma unroll
                for (int nt = 0; nt < 6; ++nt) { xpA[s][nt] = rpA[nt*16]; xpB[s][nt] = rpB[nt*16]; }
            }
            #pragma unroll
            for (int s = 0; s < 4; ++s) {
                // --- 12 MFMAs up front (A/B alternated; independent) ---
                BF8 bhA; bhA.u[0]=HdA[0]; bhA.u[1]=HdA[1]; bhA.u[2]=HdA[2]; bhA.u[3]=HdA[3];
                BF8 bhB; bhB.u[0]=HdB[0]; bhB.u[1]=HdB[1]; bhB.u[2]=HdB[2]; bhB.u[3]=HdB[3];
                f32x4 aA0 = MFMA16(Awh[0], bhA.v, FRZ[0]);
                f32x4 aB0 = MFMA16(Awh[0], bhB.v, FRZ[0]);
                f32x4 aA1 = MFMA16(Awh[1], bhA.v, FRZ[1]);
                f32x4 aB1 = MFMA16(Awh[1], bhB.v, FRZ[1]);
                f32x4 aA2 = MFMA16(Awh[2], bhA.v, FRZ[2]);
                f32x4 aB2 = MFMA16(Awh[2], bhB.v, FRZ[2]);
                f32x4 aA3 = MFMA16(Awh[3], bhA.v, FRZ[3]);
                f32x4 aB3 = MFMA16(Awh[3], bhB.v, FRZ[3]);
                f32x4 aA4 = MFMA16(Awh[4], bhA.v, BN0);
                f32x4 aB4 = MFMA16(Awh[4], bhB.v, BN0);
                f32x4 aA5 = MFMA16(Awh[5], bhA.v, BN1);
                f32x4 aB5 = MFMA16(Awh[5], bhB.v, BN1);

                // --- acts, A/B statement-interleaved (r7 math per set) ---
                float erA0 = __builtin_amdgcn_exp2f(KS * (xpA[s][0] + sel4(aA0, u)));
                float erB0 = __builtin_amdgcn_exp2f(KS * (xpB[s][0] + sel4(aB0, u)));
                float erA1 = __builtin_amdgcn_exp2f(KS * (xpA[s][1] + sel4(aA1, u)));
                float erB1 = __builtin_amdgcn_exp2f(KS * (xpB[s][1] + sel4(aB1, u)));
                float ezA0 = __builtin_amdgcn_exp2f(KS * (xpA[s][2] + sel4(aA2, u)));
                float ezB0 = __builtin_amdgcn_exp2f(KS * (xpB[s][2] + sel4(aB2, u)));
                float ezA1 = __builtin_amdgcn_exp2f(KS * (xpA[s][3] + sel4(aA3, u)));
                float ezB1 = __builtin_amdgcn_exp2f(KS * (xpB[s][3] + sel4(aB3, u)));
                float drA0 = 1.f + erA0, drA1 = 1.f + erA1;
                float drB0 = 1.f + erB0, drB1 = 1.f + erB1;
                float dzA0 = 1.f + ezA0, dzA1 = 1.f + ezA1;
                float dzB0 = 1.f + ezB0, dzB1 = 1.f + ezB1;
                float qrA = __builtin_amdgcn_rcpf(drA0 * drA1);
                float qrB = __builtin_amdgcn_rcpf(drB0 * drB1);
                float qzA = __builtin_amdgcn_rcpf(dzA0 * dzA1);
                float qzB = __builtin_amdgcn_rcpf(dzB0 * dzB1);
                float rA0 = drA1 * qrA, rA1 = drA0 * qrA;
                float rB0 = drB1 * qrB, rB1 = drB0 * qrB;
                float zA0 = dzA1 * qzA, zA1 = dzA0 * qzA;
                float zB0 = dzB1 * qzB, zB1 = dzB0 * qzB;
                float vA0 = xpA[s][4] + fn0 + rA0 * sel4(aA4, u);
                float vB0 = xpB[s][4] + fn0 + rB0 * sel4(aB4, u);
                float vA1 = xpA[s][5] + fn1 + rA1 * sel4(aA5, u);
                float vB1 = xpB[s][5] + fn1 + rB1 * sel4(aB5, u);
                float etA0 = __builtin_amdgcn_exp2f(KT * fabsf(vA0));
                float etB0 = __builtin_amdgcn_exp2f(KT * fabsf(vB0));
                float etA1 = __builtin_amdgcn_exp2f(KT * fabsf(vA1));
                float etB1 = __builtin_amdgcn_exp2f(KT * fabsf(vB1));
                float dtA0 = 1.f + etA0, dtA1 = 1.f + etA1;
                float dtB0 = 1.f + etB0, dtB1 = 1.f + etB1;
                float qtA = __builtin_amdgcn_rcpf(dtA0 * dtA1);
                float qtB = __builtin_amdgcn_rcpf(dtB0 * dtB1);
                float tA0 = copysignf((1.f - etA0) * dtA1 * qtA, vA0);
                float tB0 = copysignf((1.f - etB0) * dtB1 * qtB, vB0);
                float tA1 = copysignf((1.f - etA1) * dtA0 * qtA, vA1);
                float tB1 = copysignf((1.f - etB1) * dtB0 * qtB, vB1);
                float hALn = tA0 + zA0 * (hAL - tA0);
                float hBLn = tB0 + zB0 * (hBL - tB0);
                float hAHn = tA1 + zA1 * (hAH - tA1);
                float hBHn = tB1 + zB1 * (hBH - tB1);
                hAL = hALn; hAH = hAHn; hBL = hBLn; hBH = hBHn;

                unsigned pkA, pkB;
                asm("v_cvt_pk_bf16_f32 %0, %1, %2" : "=v"(pkA) : "v"(hALn), "v"(hAHn));
                asm("v_cvt_pk_bf16_f32 %0, %1, %2" : "=v"(pkB) : "v"(hBLn), "v"(hBHn));
                HdA[0] = QBCAST(pkA, 0);  HdB[0] = QBCAST(pkB, 0);
                HdA[1] = QBCAST(pkA, 1);  HdB[1] = QBCAST(pkB, 1);
                HdA[2] = QBCAST(pkA, 2);  HdB[2] = QBCAST(pkB, 2);
                HdA[3] = QBCAST(pkA, 3);  HdB[3] = QBCAST(pkB, 3);
            }
            barrier_nodrain();
        }

        // ---- head: lane holds fp32 h dims (q*4+u, +16) of batch bq, both sets
        const float w0 = W_head[q*4 + u], w1 = W_head[16 + q*4 + u];
        float vA = hAL * w0 + hAH * w1;
        float vB = hBL * w0 + hBH * w1;
        vA += __shfl_xor(vA, 1, 64);  vB += __shfl_xor(vB, 1, 64);
        vA += __shfl_xor(vA, 2, 64);  vB += __shfl_xor(vB, 2, 64);
        vA += __shfl_xor(vA, 16, 64); vB += __shfl_xor(vB, 16, 64);
        vA += __shfl_xor(vA, 32, 64); vB += __shfl_xor(vB, 32, 64);
        if (lane < 16 && (lane & 3) == 0) {
            float aA = vA + b_head[0];
            float eA = __builtin_amdgcn_exp2f(-1.4426950408889634f * aA);
            out[b0 + (lane >> 2)] = __builtin_amdgcn_rcpf(1.f + eA);
            float aB = vB + b_head[0];
            float eB = __builtin_amdgcn_exp2f(-1.4426950408889634f * aB);
            out[b0 + 4 + (lane >> 2)] = __builtin_amdgcn_rcpf(1.f + eB);
        }
    }
}

extern "C" void kernel_launch(void* const* d_in, const int* in_sizes, int n_in,
                              void* d_out, int out_size, void* d_ws, size_t ws_size,
                              hipStream_t stream)
{
    const float* x      = (const float*)d_in[0];
    const float* W_ih   = (const float*)d_in[1];
    const float* W_hh   = (const float*)d_in[2];
    const float* b_ih   = (const float*)d_in[3];
    const float* b_hh   = (const float*)d_in[4];
    const float* W_head = (const float*)d_in[5];
    const float* b_head = (const float*)d_in[6];
    float* out = (float*)d_out;

    gru_fused<<<256, 192, 0, stream>>>(x, W_ih, W_hh, b_ih, b_hh,
                                       W_head, b_head, out);
}

// Round 11
// 222.721 us; speedup vs baseline: 1.1876x; 1.1876x over previous
//
#include <hip/hip_runtime.h>
#include <cstdint>

// Fully-fused GRU: B=2048, T=256, F=64, H=32. fp32 in/out. ONE kernel.
// 256 blocks x 256 thr = 4 waves/block, 1 block/CU (r7 structure, best 82us).
// r10 closed the model: wall = 256 x cost(step); multi-set/co-residency can't
// reduce it. This round shrinks cost(step) itself:
//   (1) 8-step barrier groups (32 barriers vs 65): halves group-top LDS
//       first-use stall + sync skew per step. Producer double-ring stages
//       two 4-step halves per group, one group ahead.
//   (2) persistent BF8 h-fragment: QBCAST writes bh.u[w] in place — removes
//       4 v_mov/step of union rebuild.
//   (3) ALL biases folded into producer MFMA C-init (r/z: b_ih+b_hh, n: b_ih;
//       r8-verified numerics): removes 2 adds/step, chain r/z C-init = 0.
//   (4) f32x2 (v_pk_*_f32 capable) pairs for the L/H-duplicated act math.
// Chain acts otherwise byte-identical to r7 (raw v_exp2, pair-batched rcp,
// v_cvt_pk_bf16_f32, quad_perm DPP all-gather; zero memory ops on the chain).

#define TSEQ 256
#define CSTRIDE 104                                // floats per col (16B aligned)
#define NGRP 32                                    // 32 groups x 8 steps

typedef __attribute__((ext_vector_type(8))) short bf16x8;
typedef __attribute__((ext_vector_type(4))) float f32x4;
typedef __attribute__((ext_vector_type(2))) float f32x2;
union BF8 { unsigned u[4]; bf16x8 v; };

__device__ __forceinline__ unsigned bfr(float f) {            // bf16 RNE in hi16
    unsigned u = __float_as_uint(f);
    return u + 0x7fffu + ((u >> 16) & 1u);
}
__device__ __forceinline__ unsigned packhi(unsigned a, unsigned b) {
    return __builtin_amdgcn_perm(b, a, 0x07060302u);          // hi16(a)|hi16(b)<<16
}
// 8 fp32 -> hi (truncated bf16) + lo (bf16 of residual): 3-term-quality products
__device__ __forceinline__ void cvt2(const float4& f0, const float4& f1,
                                     bf16x8& hi, bf16x8& lo) {
    float f[8] = {f0.x,f0.y,f0.z,f0.w, f1.x,f1.y,f1.z,f1.w};
    BF8 H, L;
    #pragma unroll
    for (int d = 0; d < 4; ++d) {
        float a = f[2*d], b = f[2*d+1];
        unsigned ua = __float_as_uint(a), ub = __float_as_uint(b);
        float ra = a - __uint_as_float(ua & 0xffff0000u);
        float rb = b - __uint_as_float(ub & 0xffff0000u);
        H.u[d] = packhi(ua, ub);
        L.u[d] = packhi(bfr(ra), bfr(rb));
    }
    hi = H.v; lo = L.v;
}
__device__ __forceinline__ float sel4(f32x4 v, int u) {
    float a = (u & 1) ? v[1] : v[0];
    float b = (u & 1) ? v[3] : v[2];
    return (u & 2) ? b : a;
}

#define MFMA16(A, B, C) __builtin_amdgcn_mfma_f32_16x16x32_bf16((A), (B), (C), 0, 0, 0)

// quad_perm broadcast of lane w within each aligned 4-lane quad (pure VALU).
#define QBCAST(x, w) ((unsigned)__builtin_amdgcn_update_dpp( \
        0, (int)(x), ((w) | ((w)<<2) | ((w)<<4) | ((w)<<6)), 0xf, 0xf, true))

// barrier WITHOUT the compiler's vmcnt(0) drain: producers' in-flight HBM
// prefetch (needed a full group later) survives the sync.
__device__ __forceinline__ void barrier_nodrain() {
    asm volatile("s_waitcnt lgkmcnt(0)" ::: "memory");
    __builtin_amdgcn_s_barrier();
    asm volatile("" ::: "memory");
}

__global__ __launch_bounds__(256, 1)
void gru_fused(const float* __restrict__ x, const float* __restrict__ W_ih,
               const float* __restrict__ W_hh, const float* __restrict__ b_ih,
               const float* __restrict__ b_hh, const float* __restrict__ W_head,
               const float* __restrict__ b_head, float* __restrict__ out)
{
    // [buf][quad][col*CSTRIDE + nt*16 + q*4 + r]; col = batch + 4*step (0..31)
    __shared__ float xsh[2][2][32 * CSTRIDE];
    const int tid  = threadIdx.x;
    const int wid  = tid >> 6;                     // 0,1 = chain; 2,3 = producer
    const int lane = tid & 63;
    const int m = lane & 15, q = lane >> 4;
    const int b0 = blockIdx.x * 8;

    if (wid >= 2) {
        // ===================== producer (quad pq) =====================
        const int pq = wid - 2;
        const int bq = m & 3, u = m >> 2;          // col m = (batch bq, step u)
        bf16x8 Aih[6][2];
        #pragma unroll
        for (int nt = 0; nt < 6; ++nt)
            #pragma unroll
            for (int c = 0; c < 2; ++c) {
                const float* wp = W_ih + (nt*16 + m)*64 + c*32 + q*8;
                BF8 t;
                #pragma unroll
                for (int d = 0; d < 4; ++d) t.u[d] = packhi(bfr(wp[2*d]), bfr(wp[2*d+1]));
                Aih[nt][c] = t.v;
            }
        // bias C-init (rows nt*16+q*4+r): r/z tiles b_ih+b_hh, n tiles b_ih.
        f32x4 PC[6];
        #pragma unroll
        for (int nt = 0; nt < 6; ++nt) {
            f32x4 t;
            #pragma unroll
            for (int r = 0; r < 4; ++r) {
                int g = nt*16 + q*4 + r;
                t[r] = (nt < 4) ? (b_ih[g] + b_hh[g]) : b_ih[g];
            }
            PC[nt] = t;
        }
        float4 ringA[4], ringB[4];                 // two 4-step halves
        const float* xcol = x + ((size_t)(b0 + pq*4 + bq)*TSEQ + u)*64 + q*8;
        auto ldrings = [&](int grp) {
            const float* p0 = xcol + grp*512;      // half 0: steps grp*8+0..3
            const float* p1 = p0 + 256;            // half 1: steps grp*8+4..7
            ringA[0] = ((const float4*)p0)[0];        ringA[1] = ((const float4*)p0)[1];
            ringA[2] = ((const float4*)(p0+32))[0];   ringA[3] = ((const float4*)(p0+32))[1];
            ringB[0] = ((const float4*)p1)[0];        ringB[1] = ((const float4*)p1)[1];
            ringB[2] = ((const float4*)(p1+32))[0];   ringB[3] = ((const float4*)(p1+32))[1];
        };
        auto projwrite2 = [&](int buf) {           // both halves -> LDS[buf]
            bf16x8 Xh0, Xl0, Xh1, Xl1;
            cvt2(ringA[0], ringA[1], Xh0, Xl0);
            cvt2(ringA[2], ringA[3], Xh1, Xl1);
            #pragma unroll
            for (int nt = 0; nt < 6; ++nt) {
                f32x4 a = MFMA16(Aih[nt][0], Xh0, PC[nt]);
                a = MFMA16(Aih[nt][0], Xl0, a);
                a = MFMA16(Aih[nt][1], Xh1, a);
                a = MFMA16(Aih[nt][1], Xl1, a);
                *(f32x4*)&xsh[buf][pq][m*CSTRIDE + nt*16 + q*4] = a;
            }
            cvt2(ringB[0], ringB[1], Xh0, Xl0);
            cvt2(ringB[2], ringB[3], Xh1, Xl1);
            #pragma unroll
            for (int nt = 0; nt < 6; ++nt) {
                f32x4 a = MFMA16(Aih[nt][0], Xh0, PC[nt]);
                a = MFMA16(Aih[nt][0], Xl0, a);
                a = MFMA16(Aih[nt][1], Xh1, a);
                a = MFMA16(Aih[nt][1], Xl1, a);
                *(f32x4*)&xsh[buf][pq][(16 + m)*CSTRIDE + nt*16 + q*4] = a;
            }
        };
        ldrings(0);
        projwrite2(0);                             // group 0 into buf 0
        ldrings(1);
        barrier_nodrain();                         // buf0 ready
        for (int g = 0; g < NGRP; ++g) {
            if (g < NGRP - 1) {
                projwrite2((g + 1) & 1);           // chain is in buf[g&1]
                ldrings(g + 2 < NGRP ? g + 2 : NGRP - 1);
            }
            barrier_nodrain();
        }
    } else {
        // ===================== chain (quad cq) =====================
        const int cq = wid;
        const int bq = m >> 2, u = m & 3;          // replicas = consecutive lanes
        // ---- W_hh A-frags, K-permuted: pos p=q*8+j <-> dim (p>>1)+16*(p&1)
        bf16x8 Awh[6];
        #pragma unroll
        for (int nt = 0; nt < 6; ++nt) {
            const float* wp = W_hh + (nt*16 + m)*32;
            BF8 t;
            #pragma unroll
            for (int d = 0; d < 4; ++d) {
                int dd = q*4 + d;
                t.u[d] = packhi(bfr(wp[dd]), bfr(wp[dd + 16]));
            }
            Awh[nt] = t.v;
        }
        // ---- C-inits: zero for r/z (biases in producer); b_hh n-rows for n.
        const f32x4 CZ = {0.f, 0.f, 0.f, 0.f};
        f32x4 BN0, BN1;
        #pragma unroll
        for (int r = 0; r < 4; ++r) { BN0[r] = b_hh[64+q*4+r]; BN1[r] = b_hh[80+q*4+r]; }

        BF8 bh; bh.u[0]=0u; bh.u[1]=0u; bh.u[2]=0u; bh.u[3]=0u;   // persistent
        f32x2 hO = {0.f, 0.f};                     // h dims (q*4+u, +16), fp32
        barrier_nodrain();                         // buf0 ready

        const float KS = -1.4426950408889634f;     // -log2(e)   (sigmoid)
        const float KT = -2.8853900817779268f;     // -2*log2(e) (tanh)
        for (int g = 0; g < NGRP; ++g) {
            const int cbuf = g & 1;
            // group's x-pre scalars: 48 ds_read_b32, off the dep chain
            float xp[8][6];
            #pragma unroll
            for (int s = 0; s < 8; ++s) {
                const float* rp = &xsh[cbuf][cq][(bq + 4*s)*CSTRIDE + q*4 + u];
                #pragma unroll
                for (int nt = 0; nt < 6; ++nt) xp[s][nt] = rp[nt*16];
            }
            #pragma unroll
            for (int s = 0; s < 8; ++s) {
                f32x4 a0 = MFMA16(Awh[0], bh.v, CZ);
                f32x4 a1 = MFMA16(Awh[1], bh.v, CZ);
                f32x4 a2 = MFMA16(Awh[2], bh.v, CZ);
                f32x4 a3 = MFMA16(Awh[3], bh.v, CZ);
                f32x4 a4 = MFMA16(Awh[4], bh.v, BN0);
                f32x4 a5 = MFMA16(Awh[5], bh.v, BN1);

                // --- acts: raw v_exp, pair-batched rcp, f32x2 pairs ---
                float er0 = __builtin_amdgcn_exp2f(KS * (xp[s][0] + sel4(a0, u)));
                float er1 = __builtin_amdgcn_exp2f(KS * (xp[s][1] + sel4(a1, u)));
                float ez0 = __builtin_amdgcn_exp2f(KS * (xp[s][2] + sel4(a2, u)));
                float ez1 = __builtin_amdgcn_exp2f(KS * (xp[s][3] + sel4(a3, u)));
                f32x2 dr = (f32x2){er0, er1} + 1.f;
                f32x2 dz = (f32x2){ez0, ez1} + 1.f;
                float qr = __builtin_amdgcn_rcpf(dr[0] * dr[1]);
                float qz = __builtin_amdgcn_rcpf(dz[0] * dz[1]);
                f32x2 rg = (f32x2){dr[1], dr[0]} * qr;   // sigmoid(r-gates)
                f32x2 zg = (f32x2){dz[1], dz[0]} * qz;   // sigmoid(z-gates)
                float v0 = __builtin_fmaf(rg[0], sel4(a4, u), xp[s][4]);
                float v1 = __builtin_fmaf(rg[1], sel4(a5, u), xp[s][5]);
                float et0 = __builtin_amdgcn_exp2f(KT * fabsf(v0));
                float et1 = __builtin_amdgcn_exp2f(KT * fabsf(v1));
                f32x2 dt = (f32x2){et0, et1} + 1.f;
                float qt = __builtin_amdgcn_rcpf(dt[0] * dt[1]);
                float t0 = copysignf((1.f - et0) * dt[1] * qt, v0);
                float t1 = copysignf((1.f - et1) * dt[0] * qt, v1);
                f32x2 tt = {t0, t1};
                hO = tt + zg * (hO - tt);

                // B-frag all-gather within the replica quad, in place (VALU).
                unsigned pk;
                asm("v_cvt_pk_bf16_f32 %0, %1, %2" : "=v"(pk) : "v"(hO[0]), "v"(hO[1]));
                bh.u[0] = QBCAST(pk, 0);
                bh.u[1] = QBCAST(pk, 1);
                bh.u[2] = QBCAST(pk, 2);
                bh.u[3] = QBCAST(pk, 3);
            }
            barrier_nodrain();
        }

        // ---- head: lane holds fp32 h dims (q*4+u, +16) of batch bq
        float v = hO[0] * W_head[q*4 + u] + hO[1] * W_head[16 + q*4 + u];
        v += __shfl_xor(v, 1, 64);                 // sum over u (lane bits 0,1)
        v += __shfl_xor(v, 2, 64);
        v += __shfl_xor(v, 16, 64);                // sum over q (lane bits 4,5)
        v += __shfl_xor(v, 32, 64);
        if (lane < 16 && (lane & 3) == 0) {
            float a = v + b_head[0];
            float e = __builtin_amdgcn_exp2f(-1.4426950408889634f * a);
            out[b0 + cq*4 + (lane >> 2)] = __builtin_amdgcn_rcpf(1.f + e);
        }
    }
}

extern "C" void kernel_launch(void* const* d_in, const int* in_sizes, int n_in,
                              void* d_out, int out_size, void* d_ws, size_t ws_size,
                              hipStream_t stream)
{
    const float* x      = (const float*)d_in[0];
    const float* W_ih   = (const float*)d_in[1];
    const float* W_hh   = (const float*)d_in[2];
    const float* b_ih   = (const float*)d_in[3];
    const float* b_hh   = (const float*)d_in[4];
    const float* W_head = (const float*)d_in[5];
    const float* b_head = (const float*)d_in[6];
    float* out = (float*)d_out;

    gru_fused<<<256, 256, 0, stream>>>(x, W_ih, W_hh, b_ih, b_hh,
                                       W_head, b_head, out);
}